// Round 12
// baseline (297.339 us; speedup 1.0000x reference)
//
#include <hip/hip_runtime.h>
#include <math.h>

// Round 18: R16 (132.8us, best) with the conv gather LUT moved LDS -> global.
// Pipe accounting on R16 closed: VALU issue 3088 cyc/SIMD/gstep vs wall 4240
// (= measured 73% VALUBusy); DS demand ~4992 cyc/CU/gstep >= wall -> the LDS
// pipe is the limiter, and the 8 ds_read_b128 LUT gathers are its biggest
// term (~96 of 156 cyc/wave-step). The LUT is 2KB of CONSTANT data: served
// from global it is L1-resident and the gathers move to the idle vector-mem
// pipe (global_load_dwordx4, SGPR base + 32b voffset, VALU-neutral).
// Table is built by a tiny 1-block kernel into d_ws on the same stream
// (stream order -> visible; no sync calls). Bitwise-identical values and
// consumption order -> zero FP risk. __launch_bounds__(256,8) caps VGPR at
// 64 to hold 32 waves/CU. Everything else is R16 verbatim (in-register
// ballot->word selects; R17's LDS bits path reverted: it cost 8us of
// same-wave DS write->read latency). Requires T%4==0, T<=300.

typedef float v2f __attribute__((ext_vector_type(2)));
typedef unsigned long long u64;

#define DPPQ(x, ctrl) \
    __int_as_float(__builtin_amdgcn_mov_dpp(__float_as_int(x), (ctrl), 0xf, 0xf, true))

__global__ __launch_bounds__(128, 1) void build_lut_kernel(
    const float* __restrict__ conv_w, float4* __restrict__ lut_g)
{
    const int t  = threadIdx.x;        // 128 threads = 4 ky x 32 patterns
    const int ky = t >> 5, n = t & 31;
    float s00 = 0.f, s01 = 0.f, s10 = 0.f, s11 = 0.f;
#pragma unroll
    for (int kx = 0; kx < 4; ++kx) {
        const float w0 = conv_w[ky * 4 + kx];        // ch0
        const float w1 = conv_w[16 + ky * 4 + kx];   // ch1
        if ((n >> kx) & 1)       { s00 += w0; s01 += w1; }  // dx = 0
        if ((n >> (kx + 1)) & 1) { s10 += w0; s11 += w1; }  // dx = 1
    }
    lut_g[ky * 32 + n] = make_float4(s00, s01, s10, s11);
}

__global__ __launch_bounds__(256, 8) void snn_step_kernel(
    const float* __restrict__ x,       // [B,1,15,15]
    const float* __restrict__ conv_b,  // [2]
    const float* __restrict__ lin_w,   // [10,72]
    const float* __restrict__ lin_b,   // [10]
    const float4* __restrict__ glut,   // [4*32] row-LUT in global (L1-resident)
    float* __restrict__ out,           // spk_out[B,10] ++ mem_rec[T,B,10] ++ spk_rec[T,B,10]
    int T, int B)
{
    const int b   = blockIdx.x;
    const int tid = threadIdx.x;
    const int w   = tid & 63;
    const int wv  = tid >> 6;              // 0..3 = time-chunk index

    __shared__ unsigned short s_K[4][64];     // spike period per group/lane
    __shared__ float          s_p[4][2][80];  // per-wave dbuf pooled pairs
    __shared__ float          s_lin[300][10]; // lin outputs for all T steps

    // ---- phase A: period sim — wave wv owns ballot-group wv's 64 pixels ----
    {
        const int  row = 4 * wv + (w >> 4), col = w & 15;
        const bool act = (col < 15) && (row < 15);
        const float cur = act ? __fmul_rn(x[(size_t)b * 225 + row * 15 + col], 10.0f)
                              : 0.f;
        // cur <= 1.0f never spikes: vn = ve + rn(0.1*rn(cur-ve)) < cur (RN)
        int   Kp = (cur > 1.0f) ? 0 : -1;   // -1 = done-never; 0 = searching
        float ve = 0.f;
        int t = 0;
        while (t < T) {
            if (__ballot(Kp == 0) == 0ull) break;
#pragma unroll
            for (int u = 0; u < 4; ++u) {
                float vn = __fadd_rn(ve, __fmul_rn(0.1f, __fsub_rn(cur, ve)));
                bool sp = (vn > 1.0f);
                Kp = (Kp == 0 && sp) ? (t + u + 1) : Kp;
                ve = sp ? 0.f : vn;
            }
            t += 4;
        }
        s_K[wv][w] = (unsigned short)(Kp > 0 ? Kp : 0);   // 0 = never spikes
    }
    __syncthreads();

    // ---- per-lane constants ----
    const bool convlane = (w < 36);
    const int  py = w / 6, px = w - 6 * py;       // pooled coords
    const int  shx = 2 * px, shx16 = shx + 16;
    const int  poff = 20 * (w / 9) + 2 * (w - 9 * (w / 9));
    const v2f  cb2 = (v2f){conv_b[0], conv_b[1]};
    // words py..py+2 span ballots q, q+1 with q = py>>1
    const bool qe0 = ((py >> 1) == 0), qe1 = ((py >> 1) == 1);
    const bool pyodd = (py & 1) != 0;

    const int lo = w >> 2, lq = w & 3;
    v2f lw2[9];   // {W[lo][9lq+t], W[lo][36+9lq+t]}
#pragma unroll
    for (int t = 0; t < 9; ++t) {
        int i0 = lo * 72 + 9 * lq + t;
        int i1 = i0 + 36;
        lw2[t] = (v2f){lin_w[i0 < 720 ? i0 : 719], lin_w[i1 < 720 ? i1 : 719]};
    }
    const float lbias = lin_b[lo < 10 ? lo : 0];

    const int Lc = T >> 2;        // chunk length (75)
    const int t0 = wv * Lc;

    // ---- spike counters: c = K-1 - (t0 % K); spike <=> c == 0 ----
    const int Ka = s_K[0][w], Kb = s_K[1][w], Kc = s_K[2][w], Kd = s_K[3][w];
    int ca = Ka ? (Ka - 1 - t0 % Ka) : 0x0FFFFFFF;
    int cb = Kb ? (Kb - 1 - t0 % Kb) : 0x0FFFFFFF;
    int cc = Kc ? (Kc - 1 - t0 % Kc) : 0x0FFFFFFF;
    int cd = Kd ? (Kd - 1 - t0 % Kd) : 0x0FFFFFFF;

    // counters -> ballots -> this lane's 3 conv words (all in-register; R16)
    auto enc_words = [&](unsigned& wb0, unsigned& wb1, unsigned& wb2) {
        bool sp0 = (ca == 0); u64 b0 = __ballot(sp0); ca = sp0 ? (Ka - 1) : (ca - 1);
        bool sp1 = (cb == 0); u64 b1 = __ballot(sp1); cb = sp1 ? (Kb - 1) : (cb - 1);
        bool sp2 = (cc == 0); u64 b2 = __ballot(sp2); cc = sp2 ? (Kc - 1) : (cc - 1);
        bool sp3 = (cd == 0); u64 b3 = __ballot(sp3); cd = sp3 ? (Kd - 1) : (cd - 1);
        u64 balA = qe0 ? b0 : (qe1 ? b1 : b2);
        u64 balB = qe0 ? b1 : (qe1 ? b2 : b3);
        wb0 = pyodd ? (unsigned)(balA >> 32) : (unsigned)balA;
        wb1 = pyodd ? (unsigned)balB         : (unsigned)(balA >> 32);
        wb2 = pyodd ? (unsigned)(balB >> 32) : (unsigned)balB;
    };

    // conv LUT (global, L1-resident) -> interleaved pair in s_p[dbuf]
    auto conv_compute = [&](int dbuf, unsigned wb0, unsigned wb1, unsigned wb2) {
        const int i0 = (wb0 >> shx)   & 31;
        const int i1 = (wb0 >> shx16) & 31;
        const int i2 = (wb1 >> shx)   & 31;
        const int i3 = (wb1 >> shx16) & 31;
        const int i4 = (wb2 >> shx)   & 31;

        const float4 f0 = glut[i0];
        const float4 f1 = glut[32 + i1];
        const float4 f2 = glut[64 + i2];
        const float4 f3 = glut[96 + i3];
        const float4 g0 = glut[i1];
        const float4 g1 = glut[32 + i2];
        const float4 g2 = glut[64 + i3];
        const float4 g3 = glut[96 + i4];

        v2f a00 = (v2f){f0.x, f0.y};  a00 += (v2f){f1.x, f1.y};
        a00 += (v2f){f2.x, f2.y};     a00 += (v2f){f3.x, f3.y};
        v2f a01 = (v2f){f0.z, f0.w};  a01 += (v2f){f1.z, f1.w};
        a01 += (v2f){f2.z, f2.w};     a01 += (v2f){f3.z, f3.w};
        v2f a10 = (v2f){g0.x, g0.y};  a10 += (v2f){g1.x, g1.y};
        a10 += (v2f){g2.x, g2.y};     a10 += (v2f){g3.x, g3.y};
        v2f a11 = (v2f){g0.z, g0.w};  a11 += (v2f){g1.z, g1.w};
        a11 += (v2f){g2.z, g2.w};     a11 += (v2f){g3.z, g3.w};

        v2f mraw = __builtin_elementwise_max(
                       __builtin_elementwise_max(a00, a01),
                       __builtin_elementwise_max(a10, a11));
        v2f m2 = mraw + cb2;   // bias after max: rn(x+b) monotone -> exact

        *(v2f*)&s_p[wv][dbuf][poff] = m2;   // one ds_write_b64
    };

    // linear for chunk-step sm1 (reads s_p written last iteration) -> s_lin
    auto lin_step = [&](int sm1) {
        const float* base = &s_p[wv][sm1 & 1][lq * 20];
        float4 q0 = *(const float4*)(base + 0);
        float4 q1 = *(const float4*)(base + 4);
        float4 q2 = *(const float4*)(base + 8);
        float4 q3 = *(const float4*)(base + 12);
        v2f    q4 = *(const v2f*)(base + 16);
        v2f pacc = (v2f){0.f, 0.f};
        pacc = __builtin_elementwise_fma(lw2[0], (v2f){q0.x, q0.y}, pacc);
        pacc = __builtin_elementwise_fma(lw2[1], (v2f){q0.z, q0.w}, pacc);
        pacc = __builtin_elementwise_fma(lw2[2], (v2f){q1.x, q1.y}, pacc);
        pacc = __builtin_elementwise_fma(lw2[3], (v2f){q1.z, q1.w}, pacc);
        pacc = __builtin_elementwise_fma(lw2[4], (v2f){q2.x, q2.y}, pacc);
        pacc = __builtin_elementwise_fma(lw2[5], (v2f){q2.z, q2.w}, pacc);
        pacc = __builtin_elementwise_fma(lw2[6], (v2f){q3.x, q3.y}, pacc);
        pacc = __builtin_elementwise_fma(lw2[7], (v2f){q3.z, q3.w}, pacc);
        pacc = __builtin_elementwise_fma(lw2[8], q4, pacc);
        float partial = __fadd_rn(pacc.x, pacc.y);

        // quad reduce via DPP quad_perm: xor1=177, xor2=78, xor3=27
        float p1 = DPPQ(partial, 177);
        float p2 = DPPQ(partial, 78);
        float p3 = DPPQ(partial, 27);
        float lin = __fadd_rn(
            __fadd_rn(__fadd_rn(__fadd_rn(partial, p1), p2), p3), lbias);

        if (lq == 0 && lo < 10) s_lin[t0 + sm1][lo] = lin;
    };

    // ---- phase B: independent chunk, zero barriers ----
    {   // s = 0 peeled
        unsigned wb0, wb1, wb2;
        enc_words(wb0, wb1, wb2);
        if (convlane) conv_compute(0, wb0, wb1, wb2);
    }
    for (int s = 1; s < Lc; ++s) {
        unsigned wb0, wb1, wb2;
        enc_words(wb0, wb1, wb2);
        if (convlane) conv_compute(s & 1, wb0, wb1, wb2);
        lin_step(s - 1);
    }
    lin_step(Lc - 1);
    __syncthreads();

    // ---- phase C: decoder scan (wave0), exact R14 chain ----
    if (wv == 0) {
        float v = 0.f, i_syn = 0.f, sc = 0.f;
        const int o = (w < 10) ? w : 0;
        const size_t BO = (size_t)B * 10;
        float* mp  = out + BO + (size_t)b * 10 + o;
        float* spp = out + BO + (size_t)T * BO + (size_t)b * 10 + o;
#pragma unroll 4
        for (int t = 0; t < T; ++t) {
            float lv  = s_lin[t][o];
            float vd  = __fadd_rn(v, __fmul_rn(0.1f, __fsub_rn(i_syn, v)));
            float id  = __fsub_rn(i_syn, __fmul_rn(0.2f, i_syn));
            float spk = (vd > 1.0f) ? 1.0f : 0.0f;
            v = (vd > 1.0f) ? 0.0f : vd;
            sc += spk;
            i_syn = __fadd_rn(id, lv);
            if (w < 10) { *mp = v; *spp = spk; }
            mp  += BO;
            spp += BO;
        }
        if (w < 10) out[(size_t)b * 10 + w] = sc;
    }
}

extern "C" void kernel_launch(void* const* d_in, const int* in_sizes, int n_in,
                              void* d_out, int out_size, void* d_ws, size_t ws_size,
                              hipStream_t stream) {
    const float* x      = (const float*)d_in[0];
    const float* conv_w = (const float*)d_in[1];
    const float* conv_b = (const float*)d_in[2];
    const float* lin_w  = (const float*)d_in[3];
    const float* lin_b  = (const float*)d_in[4];
    float* out = (float*)d_out;

    const int B = in_sizes[0] / 225;             // x is [B,1,15,15]
    const int T = (out_size / (B * 10) - 1) / 2; // out = B*10 * (1 + 2T); T=300

    float4* lut_g = (float4*)d_ws;               // 2KB table in workspace
    build_lut_kernel<<<1, 128, 0, stream>>>(conv_w, lut_g);
    snn_step_kernel<<<B, 256, 0, stream>>>(x, conv_b, lin_w, lin_b,
                                           lut_g, out, T, B);
}

// Round 13
// 193.553 us; speedup vs baseline: 1.5362x; 1.5362x over previous
//
#include <hip/hip_runtime.h>
#include <math.h>

// Round 19: R16 (132.8us best) with the conv gathers shrunk ON the LDS pipe.
// R18 proved gathers must stay in LDS (global gathers: 240us, L1 line-split
// serialization). DS accounting: ~170 DS-cyc/wave-step, gathers = 96.
// Algebraic find: dx=1 window sum of a 5-bit row pattern == dx=0 sum of the
// SHIFTED pattern (i>>1) -> LUT needs only 4-bit dx0 patterns -> two-row
// pair tables are tiny: T01[a|(b<<4)] = {ch0,ch1} sums of rows ky=0,1 with
// patterns a,b (256 x 8B = 2KB); T23 likewise. Every (dy,dx) window sum =
// T01[..] + T23[..]:
//   dy0: (i0,i1)/(i2,i3);  dy1: (i1,i2)/(i3,i4);  dx1 uses i>>1 indices.
// 8x ds_read_b64 (~7cyc) replace 8x ds_read_b128 (~12cyc); 12 pk_adds -> 4
// (+16 cheap index ops; VALU has 27% slack). LDS 19.1KB -> still 8 blocks/CU.
// Conv FP reorder ((r01)+(r23) vs serial) = same last-ulp class as R12/R13
// (passed). Everything else R16 verbatim: periodic-encoder counters,
// in-register ballot->word selects, 4 independent chunks, s_p dbuf + lag-1
// lin, DPP quad-reduce, wave0 decoder. Requires T%4==0, T<=300.

typedef float v2f __attribute__((ext_vector_type(2)));
typedef unsigned long long u64;

#define DPPQ(x, ctrl) \
    __int_as_float(__builtin_amdgcn_mov_dpp(__float_as_int(x), (ctrl), 0xf, 0xf, true))

__global__ __launch_bounds__(256, 4) void snn_step_kernel(
    const float* __restrict__ x,       // [B,1,15,15]
    const float* __restrict__ conv_w,  // [2,1,4,4]
    const float* __restrict__ conv_b,  // [2]
    const float* __restrict__ lin_w,   // [10,72]
    const float* __restrict__ lin_b,   // [10]
    float* __restrict__ out,           // spk_out[B,10] ++ mem_rec[T,B,10] ++ spk_rec[T,B,10]
    int T, int B)
{
    const int b   = blockIdx.x;
    const int tid = threadIdx.x;
    const int w   = tid & 63;
    const int wv  = tid >> 6;              // 0..3 = time-chunk index

    __shared__ v2f            s_T01[256];     // pair LUT rows ky=0,1 (2KB)
    __shared__ v2f            s_T23[256];     // pair LUT rows ky=2,3 (2KB)
    __shared__ unsigned short s_K[4][64];     // spike period per group/lane
    __shared__ float          s_p[4][2][80];  // per-wave dbuf pooled pairs
    __shared__ float          s_lin[300][10]; // lin outputs for all T steps

    // ---- phase A1: pair-LUT build (all 256 threads, 1 entry per table) ----
    {
        const int aa = tid & 15, bb = tid >> 4;   // row patterns (4-bit, dx0)
        float x0 = 0.f, y0 = 0.f, x1 = 0.f, y1 = 0.f;   // T01 row sums
        float x2 = 0.f, y2 = 0.f, x3 = 0.f, y3 = 0.f;   // T23 row sums
#pragma unroll
        for (int kx = 0; kx < 4; ++kx) {
            const bool ba = (aa >> kx) & 1;
            const bool bbit = (bb >> kx) & 1;
            if (ba)   { x0 += conv_w[kx];      y0 += conv_w[16 + kx]; }
            if (bbit) { x1 += conv_w[4 + kx];  y1 += conv_w[20 + kx]; }
            if (ba)   { x2 += conv_w[8 + kx];  y2 += conv_w[24 + kx]; }
            if (bbit) { x3 += conv_w[12 + kx]; y3 += conv_w[28 + kx]; }
        }
        s_T01[tid] = (v2f){__fadd_rn(x0, x1), __fadd_rn(y0, y1)};
        s_T23[tid] = (v2f){__fadd_rn(x2, x3), __fadd_rn(y2, y3)};
    }

    // ---- phase A2: period sim — wave wv owns ballot-group wv's 64 pixels ----
    {
        const int  row = 4 * wv + (w >> 4), col = w & 15;
        const bool act = (col < 15) && (row < 15);
        const float cur = act ? __fmul_rn(x[(size_t)b * 225 + row * 15 + col], 10.0f)
                              : 0.f;
        // cur <= 1.0f never spikes: vn = ve + rn(0.1*rn(cur-ve)) < cur (RN)
        int   Kp = (cur > 1.0f) ? 0 : -1;   // -1 = done-never; 0 = searching
        float ve = 0.f;
        int t = 0;
        while (t < T) {
            if (__ballot(Kp == 0) == 0ull) break;
#pragma unroll
            for (int u = 0; u < 4; ++u) {
                float vn = __fadd_rn(ve, __fmul_rn(0.1f, __fsub_rn(cur, ve)));
                bool sp = (vn > 1.0f);
                Kp = (Kp == 0 && sp) ? (t + u + 1) : Kp;
                ve = sp ? 0.f : vn;
            }
            t += 4;
        }
        s_K[wv][w] = (unsigned short)(Kp > 0 ? Kp : 0);   // 0 = never spikes
    }
    __syncthreads();

    // ---- per-lane constants ----
    const bool convlane = (w < 36);
    const int  py = w / 6, px = w - 6 * py;       // pooled coords
    const int  shx = 2 * px, shx16 = shx + 16;
    const int  poff = 20 * (w / 9) + 2 * (w - 9 * (w / 9));
    const v2f  cb2 = (v2f){conv_b[0], conv_b[1]};
    // words py..py+2 span ballots q, q+1 with q = py>>1
    const bool qe0 = ((py >> 1) == 0), qe1 = ((py >> 1) == 1);
    const bool pyodd = (py & 1) != 0;

    const int lo = w >> 2, lq = w & 3;
    v2f lw2[9];   // {W[lo][9lq+t], W[lo][36+9lq+t]}
#pragma unroll
    for (int t = 0; t < 9; ++t) {
        int i0 = lo * 72 + 9 * lq + t;
        int i1 = i0 + 36;
        lw2[t] = (v2f){lin_w[i0 < 720 ? i0 : 719], lin_w[i1 < 720 ? i1 : 719]};
    }
    const float lbias = lin_b[lo < 10 ? lo : 0];

    const int Lc = T >> 2;        // chunk length (75)
    const int t0 = wv * Lc;

    // ---- spike counters: c = K-1 - (t0 % K); spike <=> c == 0 ----
    const int Ka = s_K[0][w], Kb = s_K[1][w], Kc = s_K[2][w], Kd = s_K[3][w];
    int ca = Ka ? (Ka - 1 - t0 % Ka) : 0x0FFFFFFF;
    int cb = Kb ? (Kb - 1 - t0 % Kb) : 0x0FFFFFFF;
    int cc = Kc ? (Kc - 1 - t0 % Kc) : 0x0FFFFFFF;
    int cd = Kd ? (Kd - 1 - t0 % Kd) : 0x0FFFFFFF;

    // counters -> ballots -> this lane's 3 conv words (all in-register; R16)
    auto enc_words = [&](unsigned& wb0, unsigned& wb1, unsigned& wb2) {
        bool sp0 = (ca == 0); u64 b0 = __ballot(sp0); ca = sp0 ? (Ka - 1) : (ca - 1);
        bool sp1 = (cb == 0); u64 b1 = __ballot(sp1); cb = sp1 ? (Kb - 1) : (cb - 1);
        bool sp2 = (cc == 0); u64 b2 = __ballot(sp2); cc = sp2 ? (Kc - 1) : (cc - 1);
        bool sp3 = (cd == 0); u64 b3 = __ballot(sp3); cd = sp3 ? (Kd - 1) : (cd - 1);
        u64 balA = qe0 ? b0 : (qe1 ? b1 : b2);
        u64 balB = qe0 ? b1 : (qe1 ? b2 : b3);
        wb0 = pyodd ? (unsigned)(balA >> 32) : (unsigned)balA;
        wb1 = pyodd ? (unsigned)balB         : (unsigned)(balA >> 32);
        wb2 = pyodd ? (unsigned)(balB >> 32) : (unsigned)balB;
    };

    // conv via pair-LUT (8x ds_read_b64) -> interleaved pair in s_p[dbuf]
    auto conv_compute = [&](int dbuf, unsigned wb0, unsigned wb1, unsigned wb2) {
        const int i0 = (wb0 >> shx)   & 31;
        const int i1 = (wb0 >> shx16) & 31;
        const int i2 = (wb1 >> shx)   & 31;
        const int i3 = (wb1 >> shx16) & 31;
        const int i4 = (wb2 >> shx)   & 31;

        const int a0 = i0 & 15, a1 = i1 & 15, a2 = i2 & 15;
        const int a3 = i3 & 15, a4 = i4 & 15;
        const int c0 = i0 >> 1, c1 = i1 >> 1, c2 = i2 >> 1;
        const int c3 = i3 >> 1, c4 = i4 >> 1;

        v2f p00a = s_T01[a0 | (a1 << 4)];   // dy0 dx0 rows 0,1
        v2f p00b = s_T23[a2 | (a3 << 4)];   // dy0 dx0 rows 2,3
        v2f p01a = s_T01[c0 | (c1 << 4)];   // dy0 dx1
        v2f p01b = s_T23[c2 | (c3 << 4)];
        v2f p10a = s_T01[a1 | (a2 << 4)];   // dy1 dx0
        v2f p10b = s_T23[a3 | (a4 << 4)];
        v2f p11a = s_T01[c1 | (c2 << 4)];   // dy1 dx1
        v2f p11b = s_T23[c3 | (c4 << 4)];

        v2f v00 = p00a + p00b;
        v2f v01 = p01a + p01b;
        v2f v10 = p10a + p10b;
        v2f v11 = p11a + p11b;
        v2f mraw = __builtin_elementwise_max(
                       __builtin_elementwise_max(v00, v01),
                       __builtin_elementwise_max(v10, v11));
        v2f m2 = mraw + cb2;   // bias after max: rn(x+b) monotone -> exact

        *(v2f*)&s_p[wv][dbuf][poff] = m2;   // one ds_write_b64
    };

    // linear for chunk-step sm1 (reads s_p written last iteration) -> s_lin
    auto lin_step = [&](int sm1) {
        const float* base = &s_p[wv][sm1 & 1][lq * 20];
        float4 q0 = *(const float4*)(base + 0);
        float4 q1 = *(const float4*)(base + 4);
        float4 q2 = *(const float4*)(base + 8);
        float4 q3 = *(const float4*)(base + 12);
        v2f    q4 = *(const v2f*)(base + 16);
        v2f pacc = (v2f){0.f, 0.f};
        pacc = __builtin_elementwise_fma(lw2[0], (v2f){q0.x, q0.y}, pacc);
        pacc = __builtin_elementwise_fma(lw2[1], (v2f){q0.z, q0.w}, pacc);
        pacc = __builtin_elementwise_fma(lw2[2], (v2f){q1.x, q1.y}, pacc);
        pacc = __builtin_elementwise_fma(lw2[3], (v2f){q1.z, q1.w}, pacc);
        pacc = __builtin_elementwise_fma(lw2[4], (v2f){q2.x, q2.y}, pacc);
        pacc = __builtin_elementwise_fma(lw2[5], (v2f){q2.z, q2.w}, pacc);
        pacc = __builtin_elementwise_fma(lw2[6], (v2f){q3.x, q3.y}, pacc);
        pacc = __builtin_elementwise_fma(lw2[7], (v2f){q3.z, q3.w}, pacc);
        pacc = __builtin_elementwise_fma(lw2[8], q4, pacc);
        float partial = __fadd_rn(pacc.x, pacc.y);

        // quad reduce via DPP quad_perm: xor1=177, xor2=78, xor3=27
        float p1 = DPPQ(partial, 177);
        float p2 = DPPQ(partial, 78);
        float p3 = DPPQ(partial, 27);
        float lin = __fadd_rn(
            __fadd_rn(__fadd_rn(__fadd_rn(partial, p1), p2), p3), lbias);

        if (lq == 0 && lo < 10) s_lin[t0 + sm1][lo] = lin;
    };

    // ---- phase B: independent chunk, zero barriers ----
    {   // s = 0 peeled
        unsigned wb0, wb1, wb2;
        enc_words(wb0, wb1, wb2);
        if (convlane) conv_compute(0, wb0, wb1, wb2);
    }
    for (int s = 1; s < Lc; ++s) {
        unsigned wb0, wb1, wb2;
        enc_words(wb0, wb1, wb2);
        if (convlane) conv_compute(s & 1, wb0, wb1, wb2);
        lin_step(s - 1);
    }
    lin_step(Lc - 1);
    __syncthreads();

    // ---- phase C: decoder scan (wave0), exact R14 chain ----
    if (wv == 0) {
        float v = 0.f, i_syn = 0.f, sc = 0.f;
        const int o = (w < 10) ? w : 0;
        const size_t BO = (size_t)B * 10;
        float* mp  = out + BO + (size_t)b * 10 + o;
        float* spp = out + BO + (size_t)T * BO + (size_t)b * 10 + o;
#pragma unroll 4
        for (int t = 0; t < T; ++t) {
            float lv  = s_lin[t][o];
            float vd  = __fadd_rn(v, __fmul_rn(0.1f, __fsub_rn(i_syn, v)));
            float id  = __fsub_rn(i_syn, __fmul_rn(0.2f, i_syn));
            float spk = (vd > 1.0f) ? 1.0f : 0.0f;
            v = (vd > 1.0f) ? 0.0f : vd;
            sc += spk;
            i_syn = __fadd_rn(id, lv);
            if (w < 10) { *mp = v; *spp = spk; }
            mp  += BO;
            spp += BO;
        }
        if (w < 10) out[(size_t)b * 10 + w] = sc;
    }
}

extern "C" void kernel_launch(void* const* d_in, const int* in_sizes, int n_in,
                              void* d_out, int out_size, void* d_ws, size_t ws_size,
                              hipStream_t stream) {
    const float* x      = (const float*)d_in[0];
    const float* conv_w = (const float*)d_in[1];
    const float* conv_b = (const float*)d_in[2];
    const float* lin_w  = (const float*)d_in[3];
    const float* lin_b  = (const float*)d_in[4];
    float* out = (float*)d_out;

    const int B = in_sizes[0] / 225;             // x is [B,1,15,15]
    const int T = (out_size / (B * 10) - 1) / 2; // out = B*10 * (1 + 2T); T=300

    snn_step_kernel<<<B, 256, 0, stream>>>(x, conv_w, conv_b, lin_w, lin_b,
                                           out, T, B);
}